// Round 14
// baseline (243.473 us; speedup 1.0000x reference)
//
#include <hip/hip_runtime.h>
#include <math.h>

#define N_NODES 100000
#define E_EDGES 1600000
#define D_IN    128
#define H_MID   32
#define C_OUT   5

#define BSHIFT 8
#define BNODES 256     // nodes per dst-bucket
#define NBKT   391     // ceil(100000/256)
#define BCAP   4500    // per-bucket staging cap (mean 4092, +6.4 sigma)
#define SRC_BITS 17
#define SRC_MASK 0x1FFFF

#define EB     4096    // edges per binA block (84B avg runs in drain)
#define NBA    391     // binA blocks = ceil(E/EB)
#define NMF    782     // mfma blocks (128 nodes each) = ceil(N/128)

#define KP 136         // LDS k-stride in bf16 units (x-tile and wt panel)

typedef __attribute__((ext_vector_type(8))) short bf16x8;
typedef __attribute__((ext_vector_type(4))) float f32x4;

// round-to-nearest-even fp32 -> bf16 bits
__device__ inline unsigned f2bf(float f) {
    unsigned u = __float_as_uint(f);
    return (u + 0x7FFFu + ((u >> 16) & 1u)) >> 16;
}
__device__ inline float bflo(unsigned v) { return __uint_as_float((v & 0xFFFFu) << 16); }
__device__ inline float bfhi(unsigned v) { return __uint_as_float(v & 0xFFFF0000u); }
__device__ inline float bf2f(unsigned short u) { return __uint_as_float(((unsigned)u) << 16); }

// ---- front: fused binA (blocks 0..NBA-1) + K1 MFMA (blocks NBA..) ---------
// binA: EB=4096 counting sort + fire-and-forget deg histogram (global),
// dual LDS hist, wave-0 shfl scan, scattered drain with ~84B runs.
// MFMA: 128 nodes/block, W1 panel built per-block in LDS.
__global__ __launch_bounds__(1024) void k_front(
    const int* __restrict__ src,
    const int* __restrict__ dst,
    const float* __restrict__ ew,
    int* __restrict__ bucket_cursor,
    int* __restrict__ deg_g,
    int2* __restrict__ staged,
    const float* __restrict__ x,
    const float* __restrict__ Wrel1,
    const float* __restrict__ Wroot1,
    const float* __restrict__ b1,
    unsigned short* __restrict__ xrelh,
    float* __restrict__ xroot) {
    __shared__ __align__(16) char smem[52224];
    int tid = threadIdx.x;

    if (blockIdx.x < NBA) {
        // ---------------- binA role: counting-sort 4096 edges --------------
        int2*  ebuf   = (int2*)smem;                  // @0      32768 B
        short* bbuf   = (short*)(smem + 32768);       //          8192 B
        int*   cnt0   = (int*)(smem + 40960);         //          1564 B
        int*   cnt1   = (int*)(smem + 42524);         //          1564 B
        int*   lstart = (int*)(smem + 44088);         //          1564 B
        int*   gbase  = (int*)(smem + 45652);         //          1564 B
        int*   totp   = (int*)(smem + 47216);         //             4 B
        int eBase = blockIdx.x * EB;
        int half = tid >> 9;                          // 0 or 1
        int* cntH = half ? cnt1 : cnt0;

        if (tid < NBKT) { cnt0[tid] = 0; cnt1[tid] = 0; }
        __syncthreads();

        int b[4], rank[4], packed[4], wbits[4];
        bool valid[4];
        #pragma unroll
        for (int u = 0; u < 4; ++u) {
            int e = eBase + u * 1024 + tid;
            valid[u] = (e < E_EDGES);
            b[u] = 0; rank[u] = 0; packed[u] = 0; wbits[u] = 0;
            if (valid[u]) {
                int d = dst[e];
                int s = src[e];
                wbits[u] = __float_as_int(ew[e]);
                b[u] = d >> BSHIFT;
                packed[u] = ((d & (BNODES - 1)) << SRC_BITS) | s;
                rank[u] = atomicAdd(&cntH[b[u]], 1);
                atomicAdd(&deg_g[d], 1);   // fire-and-forget degree histogram
            }
        }
        __syncthreads();

        // wave-0 shfl scan over 391 bins (cnt0+cnt1): 7 bins/lane, no barriers
        if (tid < 64) {
            int base = tid * 7;
            int loc[7];
            int s = 0;
            #pragma unroll
            for (int k = 0; k < 7; ++k) {
                int idx = base + k;
                int c = (idx < NBKT) ? (cnt0[idx] + cnt1[idx]) : 0;
                loc[k] = s;
                s += c;
            }
            int run = s;
            #pragma unroll
            for (int off = 1; off < 64; off <<= 1) {
                int t = __shfl_up(run, off, 64);
                if (tid >= off) run += t;
            }
            int excl = run - s;
            #pragma unroll
            for (int k = 0; k < 7; ++k) {
                int idx = base + k;
                if (idx < NBKT) lstart[idx] = excl + loc[k];
            }
            if (tid == 63) *totp = run;
        }
        if (tid < NBKT)
            gbase[tid] = atomicAdd(&bucket_cursor[tid], cnt0[tid] + cnt1[tid]);
        __syncthreads();
        int total = *totp;

        #pragma unroll
        for (int u = 0; u < 4; ++u) {
            if (valid[u]) {
                int rg = rank[u] + (half ? cnt0[b[u]] : 0);
                int slot = lstart[b[u]] + rg;
                ebuf[slot] = make_int2(packed[u], wbits[u]);
                bbuf[slot] = (short)b[u];
            }
        }
        __syncthreads();

        for (int t = tid; t < total; t += 1024) {
            int2 ev = ebuf[t];
            int bb = bbuf[t];
            int gpos = gbase[bb] + (t - lstart[bb]);
            if (gpos < BCAP)
                staged[(size_t)bb * BCAP + gpos] = ev;
        }
    } else {
        // ---------------- MFMA role: 128 nodes/block ------------------------
        unsigned short* xs   = (unsigned short*)smem;           // 128*KP bf16
        unsigned short* wt_l = (unsigned short*)(smem + 34816); // 64*KP bf16
        int nodeBase = (blockIdx.x - NBA) * 128;

        // stage x tile (128 rows)
        #pragma unroll
        for (int it = 0; it < 8; ++it) {
            int idx = it * 1024 + tid;     // row*64 + kpair
            int row = idx >> 6, kp = idx & 63;
            int node = nodeBase + row;
            float2 v = make_float2(0.f, 0.f);
            if (node < N_NODES)
                v = *(const float2*)(x + (size_t)node * D_IN + kp * 2);
            unsigned pk = f2bf(v.x) | (f2bf(v.y) << 16);
            *(unsigned*)(xs + row * KP + kp * 2) = pk;
        }
        // build transposed bf16 W1 panel in LDS (L2-hot reads, padded rows)
        #pragma unroll
        for (int it = 0; it < 8; ++it) {
            int i = it * 1024 + tid;       // 0..8191
            int n = i >> 7, k = i & 127;
            float v = (n < H_MID) ? Wrel1[k * H_MID + n]
                                  : Wroot1[k * H_MID + (n - H_MID)];
            wt_l[n * KP + k] = (unsigned short)f2bf(v);
        }
        __syncthreads();

        int lane = tid & 63;
        int wv = tid >> 6;                 // 0..15
        int m = lane & 15;
        int quad = lane >> 4;
        int rowBase = (wv & 7) * 16;       // wave pair shares rows
        int ntBase = (wv >> 3) * 2;        // n-tiles 0-1 or 2-3

        f32x4 acc[2];
        acc[0] = (f32x4){0.f, 0.f, 0.f, 0.f};
        acc[1] = (f32x4){0.f, 0.f, 0.f, 0.f};

        #pragma unroll
        for (int kk = 0; kk < 4; ++kk) {
            int k0 = kk * 32 + quad * 8;
            bf16x8 a = *(const bf16x8*)(xs + (rowBase + m) * KP + k0);
            #pragma unroll
            for (int t = 0; t < 2; ++t) {
                bf16x8 bb = *(const bf16x8*)(wt_l + ((ntBase + t) * 16 + m) * KP + k0);
                acc[t] = __builtin_amdgcn_mfma_f32_16x16x32_bf16(a, bb, acc[t], 0, 0, 0);
            }
        }

        #pragma unroll
        for (int t = 0; t < 2; ++t) {
            #pragma unroll
            for (int r = 0; r < 4; ++r) {
                int node = nodeBase + rowBase + quad * 4 + r;
                int colg = (ntBase + t) * 16 + m;
                if (node < N_NODES) {
                    if (colg < H_MID) {
                        xrelh[(size_t)node * H_MID + colg] =
                            (unsigned short)f2bf(acc[t][r]);
                    } else {
                        int c = colg - H_MID;
                        xroot[(size_t)node * H_MID + c] = acc[t][r] + b1[c];
                    }
                }
            }
        }
    }
}

// ---- bucket1: CSR scatter (deg precomputed) + layer1 consume + export -----
// 1 block = 1 bucket (256 nodes), 1024 threads. Histogram pass eliminated:
// degrees come from k_front's fire-and-forget global atomics.
__global__ __launch_bounds__(1024) void k_bucket1(
    const int* __restrict__ bucket_cursor,
    const int* __restrict__ deg_g,
    const int2* __restrict__ staged,
    const unsigned short* __restrict__ xrelh,
    const float* __restrict__ xroot,
    const float* __restrict__ Wrel2,
    const float* __restrict__ Wroot2,
    const float* __restrict__ b2,
    unsigned short* __restrict__ h2rel8,  // [N*8] bf16 rows (16B)
    float* __restrict__ h2root,
    int* __restrict__ csr_srcb,        // [NBKT*BCAP] per-bucket-strided src
    int* __restrict__ nst_g) {         // [N] within-bucket start
    __shared__ int2 ecsr[BCAP];            // 36000 B
    __shared__ int hist[BNODES];
    __shared__ int nstart[BNODES];
    __shared__ int cur[BNODES];
    int tid = threadIdx.x;
    int b = blockIdx.x;

    int count = bucket_cursor[b];
    if (count > BCAP) count = BCAP;
    const int2* sp = staged + (size_t)b * BCAP;

    // load degrees (computed in k_front)
    if (tid < BNODES) {
        int node = b * BNODES + tid;
        hist[tid] = (node < N_NODES) ? deg_g[node] : 0;
    }
    __syncthreads();

    // wave-0 shfl scan over 256 bins: 4 bins/lane, zero barriers
    if (tid < 64) {
        int base = tid * 4;
        int loc[4];
        int s = 0;
        #pragma unroll
        for (int k = 0; k < 4; ++k) {
            loc[k] = s;
            s += hist[base + k];
        }
        int run = s;
        #pragma unroll
        for (int off = 1; off < 64; off <<= 1) {
            int t = __shfl_up(run, off, 64);
            if (tid >= off) run += t;
        }
        int excl = run - s;
        #pragma unroll
        for (int k = 0; k < 4; ++k)
            nstart[base + k] = excl + loc[k];
    }
    __syncthreads();
    if (tid < BNODES) {
        cur[tid] = nstart[tid];
        int node = b * BNODES + tid;
        if (node < N_NODES) nst_g[node] = nstart[tid];
    }
    __syncthreads();

    for (int i = tid; i < count; i += 1024) {
        int2 ev = sp[i];
        int local = ((unsigned)ev.x) >> SRC_BITS;
        int pos = atomicAdd(&cur[local], 1);
        if (pos < BCAP)
            ecsr[pos] = make_int2(ev.x & SRC_MASK, ev.y);
    }
    __syncthreads();

    // export finished CSR (coalesced) for k_bucket2
    int* outb = csr_srcb + (size_t)b * BCAP;
    for (int i = tid; i < count; i += 1024)
        outb[i] = ecsr[i].x;

    // layer1 consume: 64 groups of 16 lanes; 4 nodes/group; 8-deep gather MLP
    int g = tid >> 4;
    int lane = tid & 15;                   // cols 2*lane, 2*lane+1
    for (int nl = g; nl < BNODES; nl += 64) {
        int node = b * BNODES + nl;
        if (node >= N_NODES) continue;
        int dg = hist[nl];
        int i = nstart[nl];
        int end = i + dg;
        if (end > BCAP) end = BCAP;

        float acc0 = 0.f, acc1 = 0.f;
        for (; i + 8 <= end; i += 8) {
            int2 e[8];
            unsigned v[8];
            #pragma unroll
            for (int u = 0; u < 8; ++u) e[u] = ecsr[i + u];
            #pragma unroll
            for (int u = 0; u < 8; ++u)
                v[u] = *(const unsigned*)(xrelh + (size_t)e[u].x * H_MID + lane * 2);
            #pragma unroll
            for (int u = 0; u < 8; ++u) {
                float w = __int_as_float(e[u].y);
                acc0 += bflo(v[u]) * w;
                acc1 += bfhi(v[u]) * w;
            }
        }
        for (; i < end; ++i) {
            int2 e0 = ecsr[i];
            unsigned v0 = *(const unsigned*)(xrelh + (size_t)e0.x * H_MID + lane * 2);
            float w0 = __int_as_float(e0.y);
            acc0 += bflo(v0) * w0;
            acc1 += bfhi(v0) * w0;
        }

        float inv = 1.0f / fmaxf((float)dg, 1.0f);
        float2 rt = *(const float2*)(xroot + (size_t)node * H_MID + lane * 2);
        float h0 = fmaxf(acc0 * inv + rt.x, 0.f);
        float h1 = fmaxf(acc1 * inv + rt.y, 0.f);

        float p[2 * C_OUT];
        #pragma unroll
        for (int j = 0; j < C_OUT; ++j) {
            p[j]         = h0 * Wrel2[(2 * lane) * C_OUT + j]
                         + h1 * Wrel2[(2 * lane + 1) * C_OUT + j];
            p[C_OUT + j] = h0 * Wroot2[(2 * lane) * C_OUT + j]
                         + h1 * Wroot2[(2 * lane + 1) * C_OUT + j];
        }
        #pragma unroll
        for (int mm = 8; mm > 0; mm >>= 1) {
            #pragma unroll
            for (int j = 0; j < 2 * C_OUT; ++j)
                p[j] += __shfl_xor(p[j], mm, 16);
        }
        if (lane == 0) {
            #pragma unroll
            for (int j = 0; j < C_OUT; ++j) {
                h2rel8[(size_t)node * 8 + j] = (unsigned short)f2bf(p[j]);
                h2root[(size_t)node * C_OUT + j] = p[C_OUT + j] + b2[j];
            }
        }
    }
}

// ---- bucket2: pipelined gather over exported CSR + log_softmax ------------
// 32 nodes/block, 8 lanes/node; h2rel is bf16 16-B rows (cache-dense).
__global__ __launch_bounds__(256) void k_bucket2(
    const int* __restrict__ deg_g,
    const int* __restrict__ nst_g,
    const int* __restrict__ csr_srcb,
    const unsigned short* __restrict__ h2rel8,
    const float* __restrict__ h2root,
    float* __restrict__ out) {
    int node = blockIdx.x * 32 + (threadIdx.x >> 3);
    int lane = threadIdx.x & 7;
    int dg  = deg_g[node];
    int beg = (node >> BSHIFT) * BCAP + nst_g[node];
    int end = beg + dg;
    int lim = ((node >> BSHIFT) + 1) * BCAP;
    if (end > lim) end = lim;
    int dgc = end - beg;

    float acc = 0.f;
    if (lane < C_OUT) {
        int i = beg;
        int nfull = dgc >> 3;
        if (nfull) {
            int s[8];
            #pragma unroll
            for (int u = 0; u < 8; ++u) s[u] = csr_srcb[i + u];
            for (int bb = 1; bb < nfull; ++bb) {
                float v[8];
                #pragma unroll
                for (int u = 0; u < 8; ++u)
                    v[u] = bf2f(h2rel8[(size_t)s[u] * 8 + lane]);
                int s2[8];
                #pragma unroll
                for (int u = 0; u < 8; ++u) s2[u] = csr_srcb[i + 8 + u];
                #pragma unroll
                for (int u = 0; u < 8; ++u) acc += v[u];
                #pragma unroll
                for (int u = 0; u < 8; ++u) s[u] = s2[u];
                i += 8;
            }
            #pragma unroll
            for (int u = 0; u < 8; ++u)
                acc += bf2f(h2rel8[(size_t)s[u] * 8 + lane]);
            i += 8;
        }
        for (; i < end; ++i)
            acc += bf2f(h2rel8[(size_t)csr_srcb[i] * 8 + lane]);
    }
    float inv = 1.0f / fmaxf((float)dg, 1.0f);
    float o = (lane < C_OUT)
                  ? acc * inv + h2root[(size_t)node * C_OUT + lane]
                  : -INFINITY;
    float m = o;
    #pragma unroll
    for (int dd = 4; dd > 0; dd >>= 1) m = fmaxf(m, __shfl_xor(m, dd, 8));
    float e = (lane < C_OUT) ? expf(o - m) : 0.f;
    float ssum = e;
    #pragma unroll
    for (int dd = 4; dd > 0; dd >>= 1) ssum += __shfl_xor(ssum, dd, 8);
    float lse = m + logf(ssum);
    if (lane < C_OUT)
        out[(size_t)node * C_OUT + lane] = o - lse;
}

extern "C" void kernel_launch(void* const* d_in, const int* in_sizes, int n_in,
                              void* d_out, int out_size, void* d_ws, size_t ws_size,
                              hipStream_t stream) {
    const float* x      = (const float*)d_in[0];
    const int*   ei     = (const int*)d_in[1];
    const float* ew     = (const float*)d_in[2];
    const float* Wrel1  = (const float*)d_in[3];
    const float* Wroot1 = (const float*)d_in[4];
    const float* b1     = (const float*)d_in[5];
    const float* Wrel2  = (const float*)d_in[6];
    const float* Wroot2 = (const float*)d_in[7];
    const float* b2     = (const float*)d_in[8];
    float* out = (float*)d_out;

    const int* src = ei;
    const int* dst = ei + E_EDGES;

    // Workspace layout (no aliasing), ~44.7 MB total:
    // cursor 2KB | deg 0.4MB | staged 14.08MB | xrelh 6.4MB | xroot 12.8MB |
    // h2rel8 1.6MB | h2root 2MB | csr_srcb 7.04MB | nst 0.4MB
    char* ws = (char*)d_ws;
    int*   bucket_cursor = (int*)ws;                               // 512
    int*   deg_g         = bucket_cursor + 512;                    // N
    int2*  staged        = (int2*)(deg_g + N_NODES);               // NBKT*BCAP
    unsigned short* xrelh = (unsigned short*)(staged + (size_t)NBKT * BCAP); // 32N
    float* xroot         = (float*)(xrelh + (size_t)N_NODES * H_MID);  // 32N f32
    unsigned short* h2rel8 = (unsigned short*)(xroot + (size_t)N_NODES * H_MID); // 8N
    float* h2root        = (float*)(h2rel8 + (size_t)N_NODES * 8); // 5N
    int*   csr_srcb      = (int*)(h2root + (size_t)N_NODES * C_OUT); // NBKT*BCAP
    int*   nst_g         = csr_srcb + (size_t)NBKT * BCAP;         // N

    // --- zero cursors + degree array (one async memset, capture-safe) ---
    hipMemsetAsync(bucket_cursor, 0, (512 + N_NODES) * sizeof(int), stream);

    // --- fused: edge binning + deg histogram (391) + MFMA proj (782) ---
    k_front<<<NBA + NMF, 1024, 0, stream>>>(src, dst, ew, bucket_cursor,
                                            deg_g, staged, x, Wrel1, Wroot1,
                                            b1, xrelh, xroot);

    // --- layer 1: scatter-only CSR + gather-mean + relu + W2 + export ---
    k_bucket1<<<NBKT, 1024, 0, stream>>>(bucket_cursor, deg_g, staged,
                                         xrelh, xroot, Wrel2, Wroot2, b2,
                                         h2rel8, h2root, csr_srcb, nst_g);

    // --- layer 2: pipelined gather over exported CSR + log_softmax ---
    k_bucket2<<<N_NODES / 32, 256, 0, stream>>>(deg_g, nst_g, csr_srcb,
                                                h2rel8, h2root, out);
}

// Round 15
// 196.239 us; speedup vs baseline: 1.2407x; 1.2407x over previous
//
#include <hip/hip_runtime.h>
#include <math.h>

#define N_NODES 100000
#define E_EDGES 1600000
#define D_IN    128
#define H_MID   32
#define C_OUT   5

#define BSHIFT 8
#define BNODES 256     // nodes per dst-bucket
#define NBKT   391     // ceil(100000/256)
#define BCAP   4500    // per-bucket staging cap (mean 4092, +6.4 sigma)
#define SRC_BITS 17
#define SRC_MASK 0x1FFFF

#define EB     4096    // edges per binA block (84B avg runs in drain)
#define NBA    391     // binA blocks = ceil(E/EB)
#define NMF    782     // mfma blocks (128 nodes each) = ceil(N/128)

#define KP 136         // LDS k-stride in bf16 units (x-tile and wt panel)

typedef __attribute__((ext_vector_type(8))) short bf16x8;
typedef __attribute__((ext_vector_type(4))) float f32x4;

// round-to-nearest-even fp32 -> bf16 bits
__device__ inline unsigned f2bf(float f) {
    unsigned u = __float_as_uint(f);
    return (u + 0x7FFFu + ((u >> 16) & 1u)) >> 16;
}
__device__ inline float bflo(unsigned v) { return __uint_as_float((v & 0xFFFFu) << 16); }
__device__ inline float bfhi(unsigned v) { return __uint_as_float(v & 0xFFFF0000u); }
__device__ inline float bf2f(unsigned short u) { return __uint_as_float(((unsigned)u) << 16); }

// ---- front: fused binA (blocks 0..NBA-1) + K1 MFMA (blocks NBA..) ---------
// 1024-thread blocks. binA: EB=4096 counting sort, dual LDS hist, wave-0
// shfl scan, scattered drain with ~84B runs. MFMA: 128 nodes/block, W1
// panel built per-block in LDS (no prep kernel).
__global__ __launch_bounds__(1024) void k_front(
    const int* __restrict__ src,
    const int* __restrict__ dst,
    const float* __restrict__ ew,
    int* __restrict__ bucket_cursor,
    int2* __restrict__ staged,
    const float* __restrict__ x,
    const float* __restrict__ Wrel1,
    const float* __restrict__ Wroot1,
    const float* __restrict__ b1,
    unsigned short* __restrict__ xrelh,
    float* __restrict__ xroot) {
    __shared__ __align__(16) char smem[52224];
    int tid = threadIdx.x;

    if (blockIdx.x < NBA) {
        // ---------------- binA role: counting-sort 4096 edges --------------
        int2*  ebuf   = (int2*)smem;                  // @0      32768 B
        short* bbuf   = (short*)(smem + 32768);       //          8192 B
        int*   cnt0   = (int*)(smem + 40960);         //          1564 B
        int*   cnt1   = (int*)(smem + 42524);         //          1564 B
        int*   lstart = (int*)(smem + 44088);         //          1564 B
        int*   gbase  = (int*)(smem + 45652);         //          1564 B
        int*   totp   = (int*)(smem + 47216);         //             4 B
        int eBase = blockIdx.x * EB;
        int half = tid >> 9;                          // 0 or 1
        int* cntH = half ? cnt1 : cnt0;

        if (tid < NBKT) { cnt0[tid] = 0; cnt1[tid] = 0; }
        __syncthreads();

        int b[4], rank[4], packed[4], wbits[4];
        bool valid[4];
        #pragma unroll
        for (int u = 0; u < 4; ++u) {
            int e = eBase + u * 1024 + tid;
            valid[u] = (e < E_EDGES);
            b[u] = 0; rank[u] = 0; packed[u] = 0; wbits[u] = 0;
            if (valid[u]) {
                int d = dst[e];
                int s = src[e];
                wbits[u] = __float_as_int(ew[e]);
                b[u] = d >> BSHIFT;
                packed[u] = ((d & (BNODES - 1)) << SRC_BITS) | s;
                rank[u] = atomicAdd(&cntH[b[u]], 1);
            }
        }
        __syncthreads();

        // wave-0 shfl scan over 391 bins (cnt0+cnt1): 7 bins/lane, no barriers
        if (tid < 64) {
            int base = tid * 7;
            int loc[7];
            int s = 0;
            #pragma unroll
            for (int k = 0; k < 7; ++k) {
                int idx = base + k;
                int c = (idx < NBKT) ? (cnt0[idx] + cnt1[idx]) : 0;
                loc[k] = s;
                s += c;
            }
            int run = s;
            #pragma unroll
            for (int off = 1; off < 64; off <<= 1) {
                int t = __shfl_up(run, off, 64);
                if (tid >= off) run += t;
            }
            int excl = run - s;
            #pragma unroll
            for (int k = 0; k < 7; ++k) {
                int idx = base + k;
                if (idx < NBKT) lstart[idx] = excl + loc[k];
            }
            if (tid == 63) *totp = run;
        }
        if (tid < NBKT)
            gbase[tid] = atomicAdd(&bucket_cursor[tid], cnt0[tid] + cnt1[tid]);
        __syncthreads();
        int total = *totp;

        #pragma unroll
        for (int u = 0; u < 4; ++u) {
            if (valid[u]) {
                int rg = rank[u] + (half ? cnt0[b[u]] : 0);
                int slot = lstart[b[u]] + rg;
                ebuf[slot] = make_int2(packed[u], wbits[u]);
                bbuf[slot] = (short)b[u];
            }
        }
        __syncthreads();

        for (int t = tid; t < total; t += 1024) {
            int2 ev = ebuf[t];
            int bb = bbuf[t];
            int gpos = gbase[bb] + (t - lstart[bb]);
            if (gpos < BCAP)
                staged[(size_t)bb * BCAP + gpos] = ev;
        }
    } else {
        // ---------------- MFMA role: 128 nodes/block ------------------------
        unsigned short* xs   = (unsigned short*)smem;           // 128*KP bf16
        unsigned short* wt_l = (unsigned short*)(smem + 34816); // 64*KP bf16
        int nodeBase = (blockIdx.x - NBA) * 128;

        // stage x tile (128 rows)
        #pragma unroll
        for (int it = 0; it < 8; ++it) {
            int idx = it * 1024 + tid;     // row*64 + kpair
            int row = idx >> 6, kp = idx & 63;
            int node = nodeBase + row;
            float2 v = make_float2(0.f, 0.f);
            if (node < N_NODES)
                v = *(const float2*)(x + (size_t)node * D_IN + kp * 2);
            unsigned pk = f2bf(v.x) | (f2bf(v.y) << 16);
            *(unsigned*)(xs + row * KP + kp * 2) = pk;
        }
        // build transposed bf16 W1 panel in LDS (L2-hot reads, padded rows)
        #pragma unroll
        for (int it = 0; it < 8; ++it) {
            int i = it * 1024 + tid;       // 0..8191
            int n = i >> 7, k = i & 127;
            float v = (n < H_MID) ? Wrel1[k * H_MID + n]
                                  : Wroot1[k * H_MID + (n - H_MID)];
            wt_l[n * KP + k] = (unsigned short)f2bf(v);
        }
        __syncthreads();

        int lane = tid & 63;
        int wv = tid >> 6;                 // 0..15
        int m = lane & 15;
        int quad = lane >> 4;
        int rowBase = (wv & 7) * 16;       // wave pair shares rows
        int ntBase = (wv >> 3) * 2;        // n-tiles 0-1 or 2-3

        f32x4 acc[2];
        acc[0] = (f32x4){0.f, 0.f, 0.f, 0.f};
        acc[1] = (f32x4){0.f, 0.f, 0.f, 0.f};

        #pragma unroll
        for (int kk = 0; kk < 4; ++kk) {
            int k0 = kk * 32 + quad * 8;
            bf16x8 a = *(const bf16x8*)(xs + (rowBase + m) * KP + k0);
            #pragma unroll
            for (int t = 0; t < 2; ++t) {
                bf16x8 bb = *(const bf16x8*)(wt_l + ((ntBase + t) * 16 + m) * KP + k0);
                acc[t] = __builtin_amdgcn_mfma_f32_16x16x32_bf16(a, bb, acc[t], 0, 0, 0);
            }
        }

        #pragma unroll
        for (int t = 0; t < 2; ++t) {
            #pragma unroll
            for (int r = 0; r < 4; ++r) {
                int node = nodeBase + rowBase + quad * 4 + r;
                int colg = (ntBase + t) * 16 + m;
                if (node < N_NODES) {
                    if (colg < H_MID) {
                        xrelh[(size_t)node * H_MID + colg] =
                            (unsigned short)f2bf(acc[t][r]);
                    } else {
                        int c = colg - H_MID;
                        xroot[(size_t)node * H_MID + c] = acc[t][r] + b1[c];
                    }
                }
            }
        }
    }
}

// ---- bucket1: in-LDS CSR build + layer1 consume + CSR export --------------
// 1 block = 1 bucket (256 nodes), 1024 threads. Dual hist/cursor halves
// the returning-atomic chains in the scatter.
__global__ __launch_bounds__(1024) void k_bucket1(
    const int* __restrict__ bucket_cursor,
    const int2* __restrict__ staged,
    const unsigned short* __restrict__ xrelh,
    const float* __restrict__ xroot,
    const float* __restrict__ Wrel2,
    const float* __restrict__ Wroot2,
    const float* __restrict__ b2,
    unsigned short* __restrict__ h2rel8,  // [N*8] bf16 rows (16B)
    float* __restrict__ h2root,
    int* __restrict__ csr_srcb,        // [NBKT*BCAP] per-bucket-strided src
    int* __restrict__ deg_g,           // [N]
    int* __restrict__ nst_g) {         // [N] within-bucket start
    __shared__ int2 ecsr[BCAP];            // 36000 B
    __shared__ int hist0[BNODES];
    __shared__ int hist1[BNODES];
    __shared__ int nstart[BNODES];
    __shared__ int cur0[BNODES];
    __shared__ int cur1[BNODES];
    int tid = threadIdx.x;
    int b = blockIdx.x;
    int half = tid >> 9;                   // 0 or 1
    int* histH = half ? hist1 : hist0;
    int* curH  = half ? cur1  : cur0;

    int count = bucket_cursor[b];
    if (count > BCAP) count = BCAP;
    const int2* sp = staged + (size_t)b * BCAP;

    if (tid < BNODES) { hist0[tid] = 0; hist1[tid] = 0; }
    __syncthreads();
    for (int i = tid; i < count; i += 1024)
        atomicAdd(&histH[((unsigned)sp[i].x) >> SRC_BITS], 1);
    __syncthreads();

    // wave-0 shfl scan over 256 bins (hist0+hist1): 4 bins/lane, no barriers
    if (tid < 64) {
        int base = tid * 4;
        int loc[4];
        int s = 0;
        #pragma unroll
        for (int k = 0; k < 4; ++k) {
            loc[k] = s;
            s += hist0[base + k] + hist1[base + k];
        }
        int run = s;
        #pragma unroll
        for (int off = 1; off < 64; off <<= 1) {
            int t = __shfl_up(run, off, 64);
            if (tid >= off) run += t;
        }
        int excl = run - s;
        #pragma unroll
        for (int k = 0; k < 4; ++k)
            nstart[base + k] = excl + loc[k];
    }
    __syncthreads();
    if (tid < BNODES) {
        int h0 = hist0[tid];
        cur0[tid] = nstart[tid];
        cur1[tid] = nstart[tid] + h0;
        int node = b * BNODES + tid;
        if (node < N_NODES) {
            deg_g[node] = h0 + hist1[tid];
            nst_g[node] = nstart[tid];
        }
    }
    __syncthreads();

    for (int i = tid; i < count; i += 1024) {
        int2 ev = sp[i];
        int local = ((unsigned)ev.x) >> SRC_BITS;
        int pos = atomicAdd(&curH[local], 1);
        ecsr[pos] = make_int2(ev.x & SRC_MASK, ev.y);
    }
    __syncthreads();

    // export finished CSR (coalesced) for k_bucket2
    int* outb = csr_srcb + (size_t)b * BCAP;
    for (int i = tid; i < count; i += 1024)
        outb[i] = ecsr[i].x;

    // layer1 consume: 64 groups of 16 lanes; 4 nodes/group; 8-deep gather MLP
    int g = tid >> 4;
    int lane = tid & 15;                   // cols 2*lane, 2*lane+1
    for (int nl = g; nl < BNODES; nl += 64) {
        int node = b * BNODES + nl;
        if (node >= N_NODES) continue;
        int dg = hist0[nl] + hist1[nl];
        int i = nstart[nl];
        int end = i + dg;

        float acc0 = 0.f, acc1 = 0.f;
        for (; i + 8 <= end; i += 8) {
            int2 e[8];
            unsigned v[8];
            #pragma unroll
            for (int u = 0; u < 8; ++u) e[u] = ecsr[i + u];
            #pragma unroll
            for (int u = 0; u < 8; ++u)
                v[u] = *(const unsigned*)(xrelh + (size_t)e[u].x * H_MID + lane * 2);
            #pragma unroll
            for (int u = 0; u < 8; ++u) {
                float w = __int_as_float(e[u].y);
                acc0 += bflo(v[u]) * w;
                acc1 += bfhi(v[u]) * w;
            }
        }
        for (; i < end; ++i) {
            int2 e0 = ecsr[i];
            unsigned v0 = *(const unsigned*)(xrelh + (size_t)e0.x * H_MID + lane * 2);
            float w0 = __int_as_float(e0.y);
            acc0 += bflo(v0) * w0;
            acc1 += bfhi(v0) * w0;
        }

        float inv = 1.0f / fmaxf((float)dg, 1.0f);
        float2 rt = *(const float2*)(xroot + (size_t)node * H_MID + lane * 2);
        float h0 = fmaxf(acc0 * inv + rt.x, 0.f);
        float h1 = fmaxf(acc1 * inv + rt.y, 0.f);

        float p[2 * C_OUT];
        #pragma unroll
        for (int j = 0; j < C_OUT; ++j) {
            p[j]         = h0 * Wrel2[(2 * lane) * C_OUT + j]
                         + h1 * Wrel2[(2 * lane + 1) * C_OUT + j];
            p[C_OUT + j] = h0 * Wroot2[(2 * lane) * C_OUT + j]
                         + h1 * Wroot2[(2 * lane + 1) * C_OUT + j];
        }
        #pragma unroll
        for (int mm = 8; mm > 0; mm >>= 1) {
            #pragma unroll
            for (int j = 0; j < 2 * C_OUT; ++j)
                p[j] += __shfl_xor(p[j], mm, 16);
        }
        if (lane == 0) {
            #pragma unroll
            for (int j = 0; j < C_OUT; ++j) {
                h2rel8[(size_t)node * 8 + j] = (unsigned short)f2bf(p[j]);
                h2root[(size_t)node * C_OUT + j] = p[C_OUT + j] + b2[j];
            }
        }
    }
}

// ---- bucket2: pipelined gather over exported CSR + log_softmax ------------
// 32 nodes/block, 8 lanes/node; h2rel is bf16 16-B rows (cache-dense).
__global__ __launch_bounds__(256) void k_bucket2(
    const int* __restrict__ deg_g,
    const int* __restrict__ nst_g,
    const int* __restrict__ csr_srcb,
    const unsigned short* __restrict__ h2rel8,
    const float* __restrict__ h2root,
    float* __restrict__ out) {
    int node = blockIdx.x * 32 + (threadIdx.x >> 3);
    int lane = threadIdx.x & 7;
    int dg  = deg_g[node];
    int beg = (node >> BSHIFT) * BCAP + nst_g[node];
    int end = beg + dg;

    float acc = 0.f;
    if (lane < C_OUT) {
        int i = beg;
        int nfull = dg >> 3;
        if (nfull) {
            int s[8];
            #pragma unroll
            for (int u = 0; u < 8; ++u) s[u] = csr_srcb[i + u];
            for (int bb = 1; bb < nfull; ++bb) {
                float v[8];
                #pragma unroll
                for (int u = 0; u < 8; ++u)
                    v[u] = bf2f(h2rel8[(size_t)s[u] * 8 + lane]);
                int s2[8];
                #pragma unroll
                for (int u = 0; u < 8; ++u) s2[u] = csr_srcb[i + 8 + u];
                #pragma unroll
                for (int u = 0; u < 8; ++u) acc += v[u];
                #pragma unroll
                for (int u = 0; u < 8; ++u) s[u] = s2[u];
                i += 8;
            }
            #pragma unroll
            for (int u = 0; u < 8; ++u)
                acc += bf2f(h2rel8[(size_t)s[u] * 8 + lane]);
            i += 8;
        }
        for (; i < end; ++i)
            acc += bf2f(h2rel8[(size_t)csr_srcb[i] * 8 + lane]);
    }
    float inv = 1.0f / fmaxf((float)dg, 1.0f);
    float o = (lane < C_OUT)
                  ? acc * inv + h2root[(size_t)node * C_OUT + lane]
                  : -INFINITY;
    float m = o;
    #pragma unroll
    for (int dd = 4; dd > 0; dd >>= 1) m = fmaxf(m, __shfl_xor(m, dd, 8));
    float e = (lane < C_OUT) ? expf(o - m) : 0.f;
    float ssum = e;
    #pragma unroll
    for (int dd = 4; dd > 0; dd >>= 1) ssum += __shfl_xor(ssum, dd, 8);
    float lse = m + logf(ssum);
    if (lane < C_OUT)
        out[(size_t)node * C_OUT + lane] = o - lse;
}

extern "C" void kernel_launch(void* const* d_in, const int* in_sizes, int n_in,
                              void* d_out, int out_size, void* d_ws, size_t ws_size,
                              hipStream_t stream) {
    const float* x      = (const float*)d_in[0];
    const int*   ei     = (const int*)d_in[1];
    const float* ew     = (const float*)d_in[2];
    const float* Wrel1  = (const float*)d_in[3];
    const float* Wroot1 = (const float*)d_in[4];
    const float* b1     = (const float*)d_in[5];
    const float* Wrel2  = (const float*)d_in[6];
    const float* Wroot2 = (const float*)d_in[7];
    const float* b2     = (const float*)d_in[8];
    float* out = (float*)d_out;

    const int* src = ei;
    const int* dst = ei + E_EDGES;

    // Workspace layout (no aliasing), ~44.7 MB total:
    // cursor 2KB | staged 14.08MB | xrelh 6.4MB | xroot 12.8MB |
    // h2rel8 1.6MB | h2root 2MB | csr_srcb 7.04MB | deg 0.4MB | nst 0.4MB
    char* ws = (char*)d_ws;
    int*   bucket_cursor = (int*)ws;                               // 512
    int2*  staged        = (int2*)(bucket_cursor + 512);           // NBKT*BCAP
    unsigned short* xrelh = (unsigned short*)(staged + (size_t)NBKT * BCAP); // 32N
    float* xroot         = (float*)(xrelh + (size_t)N_NODES * H_MID);  // 32N f32
    unsigned short* h2rel8 = (unsigned short*)(xroot + (size_t)N_NODES * H_MID); // 8N
    float* h2root        = (float*)(h2rel8 + (size_t)N_NODES * 8); // 5N
    int*   csr_srcb      = (int*)(h2root + (size_t)N_NODES * C_OUT); // NBKT*BCAP
    int*   deg_g         = csr_srcb + (size_t)NBKT * BCAP;         // N
    int*   nst_g         = deg_g + N_NODES;                        // N

    // --- zero bucket cursors (graph-capture-safe async memset) ---
    hipMemsetAsync(bucket_cursor, 0, 512 * sizeof(int), stream);

    // --- fused: edge binning (391 blocks) + dense MFMA proj (782 blocks) ---
    k_front<<<NBA + NMF, 1024, 0, stream>>>(src, dst, ew, bucket_cursor,
                                            staged, x, Wrel1, Wroot1, b1,
                                            xrelh, xroot);

    // --- layer 1: in-LDS CSR + gather-mean + relu + W2 proj + CSR export ---
    k_bucket1<<<NBKT, 1024, 0, stream>>>(bucket_cursor, staged,
                                         xrelh, xroot, Wrel2, Wroot2, b2,
                                         h2rel8, h2root, csr_srcb, deg_g, nst_g);

    // --- layer 2: pipelined gather over exported CSR + log_softmax ---
    k_bucket2<<<N_NODES / 32, 256, 0, stream>>>(deg_g, nst_g, csr_srcb,
                                                h2rel8, h2root, out);
}